// Round 10
// baseline (1265.574 us; speedup 1.0000x reference)
//
#include <hip/hip_runtime.h>

#define T_STEPS 1000
#define DT 0.1f
#define HIDDEN 128
#define N_AGENTS 1024
#define U 2
#define RING (U + 16)   // pending-accumulator slots

// tanh(x) = 1 - 2/(exp(2x)+1); exact at +/-inf, ~1e-7 rel error.
__device__ __forceinline__ float tanh_fast(float x) {
    float e = __expf(2.0f * x);
    return 1.0f - 2.0f * __builtin_amdgcn_rcpf(e + 1.0f);
}

// Opaque 16B load: asm results can't be remat'd/sunk into the loop
// (R6/R9-proven: weights stay register-file-resident, zero reload traffic).
__device__ __forceinline__ float4 opaque_load16(const float* p) {
    float4 v;
    asm volatile("global_load_dwordx4 %0, %1, off\n\ts_waitcnt vmcnt(0)"
                 : "=v"(v)
                 : "v"((unsigned long long)(uintptr_t)p)
                 : "memory");
    return v;
}

// Wave-uniform float -> SGPR (frees VGPRs).
__device__ __forceinline__ float uniformf(float v) {
    return __builtin_bit_cast(float,
        __builtin_amdgcn_readfirstlane(__builtin_bit_cast(int, v)));
}

// PUSH-MODEL + TAIL DEDUP. R9 counters: 446 cyc VALU issue per wave-step,
// of which ~300 = tanh/sincos/conc/dynamics tail computed REDUNDANTLY by
// all 4 waves. Fix: canonical state (x,y,th,c) lives in a parity-buffered
// LDS float4; one rotating OWNER wave (wave == t&3 -> SIMD-balanced)
// computes the tail once per step and publishes it; the other 3 waves
// read 16B and push. Second barrier per step added (A: pbf ready,
// B: new state ready). S_c/S_u become per-wave partials (owner steps
// only), reduced at the end. Math is op-for-op identical to R9.
//
// Wave (r,h): lane owns row 64r+lane, ages 16h..16h+15 (64 opaque-pinned
// weight floats/lane — the R6-proven no-spill envelope).
__global__ __launch_bounds__(256)
__attribute__((amdgpu_waves_per_eu(3, 4)))
void sim_kernel(const float* __restrict__ target_pos,
                const float* __restrict__ logsigma,
                const float* __restrict__ x_inits,
                const float* W1,
                const float* __restrict__ b1,
                const float* __restrict__ W2,
                const float* __restrict__ b2,
                float2* __restrict__ ws) {
    const int agent = blockIdx.x;
    const int tid  = threadIdx.x;   // 0..255
    const int wave = tid >> 6;      // 0..3
    const int lane = tid & 63;
    const int r    = wave >> 1;     // row-group: rows 64r+lane
    const int h    = wave & 1;      // age-half: ages 16h..16h+15
    const int row  = (r << 6) + lane;

    __shared__ float part1[2][32][64];        // h=1 -> h=0, 16-step delay
    __shared__ alignas(16) float pbf[2][4];   // [parity][r*2 + (0:p0|1:p1)]
    __shared__ alignas(16) float4 e4buf[2];   // [parity] canonical state
    __shared__ float2 sred[4];                // final S_c/S_u reduce

    const float tx0 = uniformf(target_pos[0]), ty0 = uniformf(target_pos[1]);
    const float tx1 = uniformf(target_pos[2]), ty1 = uniformf(target_pos[3]);
    const float tx2 = uniformf(target_pos[4]), ty2 = uniformf(target_pos[5]);
    const float is0 = uniformf(1.0f / expf(logsigma[0]));
    const float is1 = uniformf(1.0f / expf(logsigma[1]));
    const float is2 = uniformf(1.0f / expf(logsigma[2]));

    // 48 position + 16 conc weights for (row, ages 16h..16h+15).
    float Wp[48], Wc[16];
    {
        const float* rowp = W1 + row * 128;
        #pragma unroll
        for (int i = 0; i < 12; ++i) {
            float4 v = opaque_load16(rowp + 48 * h + 4 * i);
            Wp[4*i] = v.x; Wp[4*i+1] = v.y; Wp[4*i+2] = v.z; Wp[4*i+3] = v.w;
        }
        #pragma unroll
        for (int i = 0; i < 4; ++i) {
            float4 v = opaque_load16(rowp + 96 + 16 * h + 4 * i);
            Wc[4*i] = v.x; Wc[4*i+1] = v.y; Wc[4*i+2] = v.z; Wc[4*i+3] = v.w;
        }
    }
    const float b1r   = b1[row];                      // h=0 relu bias
    const float w2own = W2[(lane & 1) * HIDDEN + row];
    const float w2oth = W2[((lane & 1) ^ 1) * HIDDEN + row];
    const float b2x = uniformf(b2[0]), b2y = uniformf(b2[1]);

    auto conc = [&](float px, float py) {
        float dx0 = px - tx0, dy0 = py - ty0;
        float dx1 = px - tx1, dy1 = py - ty1;
        float dx2 = px - tx2, dy2 = py - ty2;
        float cc  = is0 * __expf(-(dx0*dx0 + dy0*dy0) * is0);
        cc       += is1 * __expf(-(dx1*dx1 + dy1*dy1) * is1);
        cc       += is2 * __expf(-(dx2*dx2 + dy2*dy2) * is2);
        return cc;
    };

    // Initial state (one-time, all lanes; needed for the ring seed anyway).
    const float x0  = uniformf(x_inits[3 * agent]);
    const float y0  = uniformf(x_inits[3 * agent + 1]);
    const float th0 = uniformf(x_inits[3 * agent + 2]);
    const float c0  = conc(x0, y0);

    // Seed pending ring: history pre-filled with e(0).
    // R[k] = sum_{m=k..15} Wloc[m]·e(0)  (slot k <-> step k+16h).
    float R[RING];
    #pragma unroll
    for (int i = 16; i < RING; ++i) R[i] = 0.f;
    {
        float acc = 0.f;
        #pragma unroll
        for (int k = 15; k >= 0; --k) {
            acc = fmaf(Wp[3*k], x0,
                   fmaf(Wp[3*k+1], y0,
                    fmaf(Wp[3*k+2], th0,
                     fmaf(Wc[k], c0, acc))));
            R[k] = acc;
        }
    }
    // h=1 partials for steps 0..15 = full e(0) sum = R[0].
    if (h == 1) {
        #pragma unroll
        for (int s = 0; s < 16; ++s) part1[r][s][lane] = R[0];
    }
    // e4buf[1] = state(0): owner of step 0 reads e4buf[(0+1)&1].
    if (tid == 0) e4buf[1] = make_float4(x0, y0, th0, c0);
    __syncthreads();

    float S_c = 0.f, S_u = 0.f;
    int t = 0;

    #pragma unroll 1
    for (int tt = 0; tt < T_STEPS / U; ++tt) {
        #pragma unroll
        for (int j = 0; j < U; ++j, ++t) {
            // ---- phase 1: h=0 finishes h(t) + layer-2; h=1 ships ----
            if (h == 0) {
                float hv = fmaxf(R[j] + part1[r][t & 31][lane] + b1r, 0.f);
                float p = w2own * hv + __shfl_xor(w2oth * hv, 1);
                #pragma unroll
                for (int off = 2; off <= 32; off <<= 1)
                    p += __shfl_xor(p, off);
                if (lane < 2) pbf[t & 1][r * 2 + lane] = p;
            } else {
                part1[r][(t + 16) & 31][lane] = R[j];
            }
            __syncthreads();   // A: pbf / part1 visible

            // ---- phase 2: OWNER wave computes the tail once ----
            if (wave == (t & 3)) {
                float4 eo = e4buf[(t + 1) & 1];          // state(t)
                float4 pa = *(const float4*)pbf[t & 1];
                float P0 = pa.x + pa.z;
                float P1 = pa.y + pa.w;
                float v  = tanh_fast(P0 + b2x);
                float wv = tanh_fast(P1 + b2y);
                S_u += v * v + wv * wv;
                float sn = __sinf(eo.z), cs = __cosf(eo.z);
                float dv = DT * v;
                float nx  = fmaf(dv, cs, eo.x);
                float ny  = fmaf(dv, sn, eo.y);
                float nth = fmaf(DT, wv, eo.z);
                float nc  = conc(nx, ny);
                S_c += nc;
                if (lane == 0) e4buf[t & 1] = make_float4(nx, ny, nth, nc);
            }
            __syncthreads();   // B: state(t+1) visible

            // ---- phase 3: everyone pushes e(t+1): 64 FMAs ----
            float4 e = e4buf[t & 1];
            #pragma unroll
            for (int k = 0; k < 16; ++k) {
                R[j+1+k] = fmaf(Wp[3*k], e.x,
                            fmaf(Wp[3*k+1], e.y,
                             fmaf(Wp[3*k+2], e.z,
                              fmaf(Wc[k], e.w, R[j+1+k]))));
            }
        }
        // ---- rotate pending ring by U ----
        #pragma unroll
        for (int i = 0; i < 16; ++i) R[i] = R[i + U];
        #pragma unroll
        for (int i = 16; i < RING; ++i) R[i] = 0.f;
    }

    // ---- combine per-wave partial sums (each wave owned 250 steps) ----
    if (lane == 0) sred[wave] = make_float2(S_c, S_u);
    __syncthreads();
    if (tid == 0) {
        float2 a = sred[0], b = sred[1], cc = sred[2], d = sred[3];
        ws[agent] = make_float2((a.x + b.x) + (cc.x + d.x),
                                (a.y + b.y) + (cc.y + d.y));
    }
}

__global__ void reduce_kernel(const float2* __restrict__ ws,
                              float* __restrict__ out) {
    const int tid = threadIdx.x;  // 256 threads
    float sc = 0.f, su = 0.f;
    for (int i = tid; i < N_AGENTS; i += 256) {
        float2 v = ws[i];
        sc += v.x;
        su += v.y;
    }
    #pragma unroll
    for (int off = 32; off > 0; off >>= 1) {
        sc += __shfl_xor(sc, off);
        su += __shfl_xor(su, off);
    }
    __shared__ float2 partw[4];
    int wave = tid >> 6;
    if ((tid & 63) == 0) partw[wave] = make_float2(sc, su);
    __syncthreads();
    if (tid == 0) {
        float SC = partw[0].x + partw[1].x + partw[2].x + partw[3].x;
        float SU = partw[0].y + partw[1].y + partw[2].y + partw[3].y;
        const float invNT  = 1.0f / (float)(N_AGENTS * T_STEPS);
        const float invNT2 = 1.0f / (float)(N_AGENTS * T_STEPS * 2);
        out[0] = -SC * invNT + SU * invNT2;
    }
}

extern "C" void kernel_launch(void* const* d_in, const int* in_sizes, int n_in,
                              void* d_out, int out_size, void* d_ws, size_t ws_size,
                              hipStream_t stream) {
    const float* target_pos = (const float*)d_in[0];
    const float* logsigma   = (const float*)d_in[1];
    const float* x_inits    = (const float*)d_in[2];
    const float* W1         = (const float*)d_in[3];
    const float* b1         = (const float*)d_in[4];
    const float* W2         = (const float*)d_in[5];
    const float* b2         = (const float*)d_in[6];
    float2* ws = (float2*)d_ws;

    sim_kernel<<<N_AGENTS, 256, 0, stream>>>(target_pos, logsigma, x_inits,
                                             W1, b1, W2, b2, ws);
    reduce_kernel<<<1, 256, 0, stream>>>(ws, (float*)d_out);
}

// Round 11
// 1025.614 us; speedup vs baseline: 1.2340x; 1.2340x over previous
//
#include <hip/hip_runtime.h>

#define T_STEPS 1000
#define DT 0.1f
#define HIDDEN 128
#define N_AGENTS 1024
#define U 2
#define RING (U + 16)   // pending-accumulator slots

// tanh(x) = 1 - 2/(exp(2x)+1); exact at +/-inf, ~1e-7 rel error.
__device__ __forceinline__ float tanh_fast(float x) {
    float e = __expf(2.0f * x);
    return 1.0f - 2.0f * __builtin_amdgcn_rcpf(e + 1.0f);
}

// Opaque 16B load: asm results can't be remat'd/sunk into the loop
// (R6/R9-proven: weights stay register-file-resident, zero reload traffic).
__device__ __forceinline__ float4 opaque_load16(const float* p) {
    float4 v;
    asm volatile("global_load_dwordx4 %0, %1, off\n\ts_waitcnt vmcnt(0)"
                 : "=v"(v)
                 : "v"((unsigned long long)(uintptr_t)p)
                 : "memory");
    return v;
}

// Wave-uniform float -> SGPR (frees VGPRs).
__device__ __forceinline__ float uniformf(float v) {
    return __builtin_bit_cast(float,
        __builtin_amdgcn_readfirstlane(__builtin_bit_cast(int, v)));
}

// Full-wave (64-lane) sum via DPP row ops on the VALU pipe (~50 cyc latency)
// instead of 6 chained ds-pipe shuffles (~200 cyc). Result broadcast via
// readlane(63) -> SGPR.
__device__ __forceinline__ float wave_sum_dpp(float x) {
    float t;
    #define DPPADD(ctrl, rmask)                                              \
        t = __builtin_bit_cast(float, __builtin_amdgcn_update_dpp(           \
                0, __builtin_bit_cast(int, x), ctrl, rmask, 0xf, false));    \
        x += t;
    DPPADD(0x111, 0xf)   // row_shr:1
    DPPADD(0x112, 0xf)   // row_shr:2
    DPPADD(0x114, 0xf)   // row_shr:4
    DPPADD(0x118, 0xf)   // row_shr:8  -> lane15 of each row = row sum
    DPPADD(0x142, 0xa)   // row_bcast15 -> rows 1,3
    DPPADD(0x143, 0xc)   // row_bcast31 -> rows 2,3; lane63 = full sum
    #undef DPPADD
    return __builtin_bit_cast(float,
        __builtin_amdgcn_readlane(__builtin_bit_cast(int, x), 63));
}

// PUSH-MODEL + TAIL DEDUP, with the R10 convoy bug fixed.
// R10 post-mortem: owner = t&3 put every block's owner wave on the SAME
// SIMD (wave-index -> SIMD is fixed; blocks run near-lockstep), so one
// SIMD serialized 4 owner tails while 3 SIMDs idled at barrier B
// (VALUBusy 38%, wall 3040 cyc/step vs ~1000 issue). Fix: owner =
// (t + blockIdx) & 3 spreads owners across SIMDs.
//
// Wave (r,h): lane owns row 64r+lane, ages 16h..16h+15 (64 opaque-pinned
// weight floats/lane — the proven no-spill envelope at waves_per_eu(3,4)).
__global__ __launch_bounds__(256)
__attribute__((amdgpu_waves_per_eu(3, 4)))
void sim_kernel(const float* __restrict__ target_pos,
                const float* __restrict__ logsigma,
                const float* __restrict__ x_inits,
                const float* W1,
                const float* __restrict__ b1,
                const float* __restrict__ W2,
                const float* __restrict__ b2,
                float2* __restrict__ ws) {
    const int agent = blockIdx.x;
    const int tid  = threadIdx.x;   // 0..255
    const int wave = tid >> 6;      // 0..3
    const int lane = tid & 63;
    const int r    = wave >> 1;     // row-group: rows 64r+lane
    const int h    = wave & 1;      // age-half: ages 16h..16h+15
    const int row  = (r << 6) + lane;
    const int obase = agent & 3;    // owner decorrelation offset

    __shared__ float part1[2][32][64];         // h=1 -> h=0, 16-step delay
    __shared__ alignas(16) float2 pbf2[2][2];  // [parity][r] = (q0sum,q1sum)
    __shared__ alignas(16) float4 e4buf[2];    // [parity] canonical state
    __shared__ float2 sred[4];                 // final S_c/S_u reduce

    const float tx0 = uniformf(target_pos[0]), ty0 = uniformf(target_pos[1]);
    const float tx1 = uniformf(target_pos[2]), ty1 = uniformf(target_pos[3]);
    const float tx2 = uniformf(target_pos[4]), ty2 = uniformf(target_pos[5]);
    const float is0 = uniformf(1.0f / expf(logsigma[0]));
    const float is1 = uniformf(1.0f / expf(logsigma[1]));
    const float is2 = uniformf(1.0f / expf(logsigma[2]));

    // 48 position + 16 conc weights for (row, ages 16h..16h+15).
    float Wp[48], Wc[16];
    {
        const float* rowp = W1 + row * 128;
        #pragma unroll
        for (int i = 0; i < 12; ++i) {
            float4 v = opaque_load16(rowp + 48 * h + 4 * i);
            Wp[4*i] = v.x; Wp[4*i+1] = v.y; Wp[4*i+2] = v.z; Wp[4*i+3] = v.w;
        }
        #pragma unroll
        for (int i = 0; i < 4; ++i) {
            float4 v = opaque_load16(rowp + 96 + 16 * h + 4 * i);
            Wc[4*i] = v.x; Wc[4*i+1] = v.y; Wc[4*i+2] = v.z; Wc[4*i+3] = v.w;
        }
    }
    const float b1r = b1[row];                 // h=0 relu bias
    const float w2a = W2[row];                 // W2 row 0 (h=0 use)
    const float w2b = W2[HIDDEN + row];        // W2 row 1 (h=0 use)
    const float b2x = uniformf(b2[0]), b2y = uniformf(b2[1]);

    auto conc = [&](float px, float py) {
        float dx0 = px - tx0, dy0 = py - ty0;
        float dx1 = px - tx1, dy1 = py - ty1;
        float dx2 = px - tx2, dy2 = py - ty2;
        float cc  = is0 * __expf(-(dx0*dx0 + dy0*dy0) * is0);
        cc       += is1 * __expf(-(dx1*dx1 + dy1*dy1) * is1);
        cc       += is2 * __expf(-(dx2*dx2 + dy2*dy2) * is2);
        return cc;
    };

    // Initial state.
    const float x0  = uniformf(x_inits[3 * agent]);
    const float y0  = uniformf(x_inits[3 * agent + 1]);
    const float th0 = uniformf(x_inits[3 * agent + 2]);
    const float c0  = conc(x0, y0);

    // Seed pending ring: history pre-filled with e(0).
    float R[RING];
    #pragma unroll
    for (int i = 16; i < RING; ++i) R[i] = 0.f;
    {
        float acc = 0.f;
        #pragma unroll
        for (int k = 15; k >= 0; --k) {
            acc = fmaf(Wp[3*k], x0,
                   fmaf(Wp[3*k+1], y0,
                    fmaf(Wp[3*k+2], th0,
                     fmaf(Wc[k], c0, acc))));
            R[k] = acc;
        }
    }
    if (h == 1) {
        #pragma unroll
        for (int s = 0; s < 16; ++s) part1[r][s][lane] = R[0];
    }
    if (tid == 0) e4buf[1] = make_float4(x0, y0, th0, c0);
    __syncthreads();

    float pl = part1[r][0][lane];   // prefetched h=1 partial for step 0
    float S_c = 0.f, S_u = 0.f;
    int t = 0;

    #pragma unroll 1
    for (int tt = 0; tt < T_STEPS / U; ++tt) {
        #pragma unroll
        for (int j = 0; j < U; ++j, ++t) {
            // ---- phase 1: h=0 completes h(t) + layer-2; h=1 ships ----
            if (h == 0) {
                float hv = fmaxf(R[j] + pl + b1r, 0.f);
                float s0 = wave_sum_dpp(w2a * hv);
                float s1 = wave_sum_dpp(w2b * hv);
                if (lane == 0) pbf2[t & 1][r] = make_float2(s0, s1);
            } else {
                part1[r][(t + 16) & 31][lane] = R[j];
            }
            __syncthreads();   // A: pbf2 / part1 visible

            // ---- phase 2: rotating owner wave computes the tail once ----
            if (wave == ((t + obase) & 3)) {
                float4 eo = e4buf[(t + 1) & 1];              // state(t)
                float4 pa = *(const float4*)&pbf2[t & 1][0];
                float P0 = pa.x + pa.z;
                float P1 = pa.y + pa.w;
                float v  = tanh_fast(P0 + b2x);
                float wv = tanh_fast(P1 + b2y);
                S_u += v * v + wv * wv;
                float sn = __sinf(eo.z), cs = __cosf(eo.z);
                float dv = DT * v;
                float nx  = fmaf(dv, cs, eo.x);
                float ny  = fmaf(dv, sn, eo.y);
                float nth = fmaf(DT, wv, eo.z);
                float nc  = conc(nx, ny);
                S_c += nc;
                if (lane == 0) e4buf[t & 1] = make_float4(nx, ny, nth, nc);
            }
            __syncthreads();   // B: state(t+1) visible

            // ---- phase 3: everyone pushes e(t+1): 64 FMAs ----
            float4 e = e4buf[t & 1];
            pl = part1[r][(t + 1) & 31][lane];   // prefetch next (safe:
                                                 // written >=16 steps ago)
            #pragma unroll
            for (int k = 0; k < 16; ++k) {
                R[j+1+k] = fmaf(Wp[3*k], e.x,
                            fmaf(Wp[3*k+1], e.y,
                             fmaf(Wp[3*k+2], e.z,
                              fmaf(Wc[k], e.w, R[j+1+k]))));
            }
        }
        // ---- rotate pending ring by U ----
        #pragma unroll
        for (int i = 0; i < 16; ++i) R[i] = R[i + U];
        #pragma unroll
        for (int i = 16; i < RING; ++i) R[i] = 0.f;
    }

    // ---- combine per-wave partial sums (each wave owned 250 steps) ----
    if (lane == 0) sred[wave] = make_float2(S_c, S_u);
    __syncthreads();
    if (tid == 0) {
        float2 a = sred[0], b = sred[1], cc = sred[2], d = sred[3];
        ws[agent] = make_float2((a.x + b.x) + (cc.x + d.x),
                                (a.y + b.y) + (cc.y + d.y));
    }
}

__global__ void reduce_kernel(const float2* __restrict__ ws,
                              float* __restrict__ out) {
    const int tid = threadIdx.x;  // 256 threads
    float sc = 0.f, su = 0.f;
    for (int i = tid; i < N_AGENTS; i += 256) {
        float2 v = ws[i];
        sc += v.x;
        su += v.y;
    }
    #pragma unroll
    for (int off = 32; off > 0; off >>= 1) {
        sc += __shfl_xor(sc, off);
        su += __shfl_xor(su, off);
    }
    __shared__ float2 partw[4];
    int wave = tid >> 6;
    if ((tid & 63) == 0) partw[wave] = make_float2(sc, su);
    __syncthreads();
    if (tid == 0) {
        float SC = partw[0].x + partw[1].x + partw[2].x + partw[3].x;
        float SU = partw[0].y + partw[1].y + partw[2].y + partw[3].y;
        const float invNT  = 1.0f / (float)(N_AGENTS * T_STEPS);
        const float invNT2 = 1.0f / (float)(N_AGENTS * T_STEPS * 2);
        out[0] = -SC * invNT + SU * invNT2;
    }
}

extern "C" void kernel_launch(void* const* d_in, const int* in_sizes, int n_in,
                              void* d_out, int out_size, void* d_ws, size_t ws_size,
                              hipStream_t stream) {
    const float* target_pos = (const float*)d_in[0];
    const float* logsigma   = (const float*)d_in[1];
    const float* x_inits    = (const float*)d_in[2];
    const float* W1         = (const float*)d_in[3];
    const float* b1         = (const float*)d_in[4];
    const float* W2         = (const float*)d_in[5];
    const float* b2         = (const float*)d_in[6];
    float2* ws = (float2*)d_ws;

    sim_kernel<<<N_AGENTS, 256, 0, stream>>>(target_pos, logsigma, x_inits,
                                             W1, b1, W2, b2, ws);
    reduce_kernel<<<1, 256, 0, stream>>>(ws, (float*)d_out);
}